// Round 16
// baseline (150.138 us; speedup 1.0000x reference)
//
#include <hip/hip_runtime.h>

// CRF loss: A=8, S=200, B=64, T=32. scores (A,S,B,T,T) f32, targets (A,S,B) i32,
// mask (S,B) bool, a_mask (A,B) bool -- bool width (u8 vs i32) runtime-detected.
// Base = R12 (PASSED 80.5us): 8-wave block per chain, wave 0 producer+consumer,
// named A/B producer register sets with 2-phase latency cover, raw lgkm-only
// barrier, runtime consumer j-loop (unroll is miscompile-cursed: R8/R9/R10).
// NEW: consumer PING-PONG e-prefetch -- step j issues step j+1's 16 independent
// ds_reads into the alternate static register array (branch ping-pong, no
// runtime indexing), so e-load latency hides under the w-dependency chain.
constexpr int A_ = 8, S_ = 200, B_ = 64, T_ = 32;
constexpr int START_TAG = 30, END_TAG = 31;
constexpr int NW = 8;                      // waves per block = tiles per phase
#define LOG2E 1.44269504088896340736f
#define LN2   0.69314718055994530942f

#if __has_builtin(__builtin_amdgcn_exp2f)
#define EXP2F(x) __builtin_amdgcn_exp2f(x)
#else
#define EXP2F(x) __expf((x) * LN2)
#endif

__device__ __forceinline__ int load_flag(const void* p, bool u8, int idx) {
    return u8 ? (int)((const unsigned char*)p)[idx] : ((const int*)p)[idx];
}

// LDS-writes-visible barrier WITHOUT vmcnt drain (proven R7/R12).
#define LGKM_BARRIER do {                                                \
        asm volatile("s_waitcnt lgkmcnt(0)" ::: "memory");               \
        __builtin_amdgcn_s_barrier();                                    \
        asm volatile("" ::: "memory");                                   \
    } while (0)

__global__ __launch_bounds__(NW * 64)
void crf_loss_kernel(const float* __restrict__ scores,
                     const int* __restrict__ targets,
                     const void* __restrict__ mask,
                     const void* __restrict__ amask,
                     float* __restrict__ out)
{
    const int chain = blockIdx.x;          // 0..511
    const int a = chain >> 6;
    const int b = chain & (B_ - 1);
    const int tid = threadIdx.x;
    const int wv = tid >> 6;               // wave 0..7 (wave 0 also consumes)
    const int lane = tid & 63;
    const int t = lane & 31;
    const int fbase = (lane >> 5) << 4;    // 0 or 16

    // bool width detect: mask row 0 is all-true. int view: 1 -> int32, 0x01010101 -> uint8
    const bool bool_u8 = (((const int*)mask)[0] != 1);
    if (!load_flag(amask, bool_u8, a * B_ + b)) return;   // uniform block exit

    __shared__ __align__(16) float ebuf[2][NW][T_ * T_];  // 2 x 8 x 4KB exp-tiles
    __shared__ float gside[2][NW];                        // raw gold-path scores
    __shared__ int tg_lds[S_];
    __shared__ float wlds[T_];                            // w vector (wave 0 only)

    // ---- first false mask index L (prefix mask) ----
    int L = S_;
    for (int base = 0; base < S_; base += 64) {
        int i = base + lane;
        int mv = (i < S_) ? load_flag(mask, bool_u8, i * B_ + b) : 1;
        unsigned long long bal = __ballot(mv == 0);
        if (bal != 0ull && L == S_) L = base + (int)__builtin_ctzll(bal);
    }

    for (int i = tid; i < S_; i += NW * 64)
        tg_lds[i] = targets[((size_t)a * S_ + i) * B_ + b];
    __syncthreads();                        // tg_lds ready (drain fine in prologue)

    const size_t s_stride = (size_t)B_ * T_ * T_;         // 65536 floats per step
    const float* cb = scores + ((size_t)a * S_ * B_ + b) * (T_ * T_);

    float wcur = 0.0f, C2 = 0.0f, tg = 0.0f;
    if (wv == 0) {                          // consumer init
        wcur = EXP2F(cb[START_TAG * T_ + t] * LOG2E);
        if (lane < 32) wlds[lane] = wcur;
        tg = cb[tg_lds[0]];
    }

    const int nch = (L - 1 + NW - 1) / NW;  // phases (block-uniform)

#define E4(DST, SRC) do {                                                \
        DST.x = EXP2F(SRC.x * LOG2E); DST.y = EXP2F(SRC.y * LOG2E);      \
        DST.z = EXP2F(SRC.z * LOG2E); DST.w = EXP2F(SRC.w * LOG2E);      \
    } while (0)

#define RENORM do {                                                      \
        float m_ = wcur;                                                 \
        m_ = fmaxf(m_, __shfl_xor(m_, 1));                               \
        m_ = fmaxf(m_, __shfl_xor(m_, 2));                               \
        m_ = fmaxf(m_, __shfl_xor(m_, 4));                               \
        m_ = fmaxf(m_, __shfl_xor(m_, 8));                               \
        m_ = fmaxf(m_, __shfl_xor(m_, 16));                              \
        int eb_ = (__float_as_int(m_) >> 23) & 0xff;                     \
        C2 += (float)(eb_ - 127);                                        \
        float sc2_ = __int_as_float((254 - eb_) << 23);                  \
        wcur *= sc2_;                                                    \
        if (lane < 32) wlds[lane] = wcur;                                \
    } while (0)

#define TLOAD(Q0, Q1, Q2, Q3, GR, SC) do {                               \
        const int s_ = (SC);                                             \
        if (s_ < L) {                                                    \
            const float*  p_  = cb + (size_t)s_ * s_stride;              \
            const float4* p4_ = (const float4*)p_;                       \
            Q0 = p4_[lane];       Q1 = p4_[64 + lane];                   \
            Q2 = p4_[128 + lane]; Q3 = p4_[192 + lane];                  \
            GR = p_[tg_lds[s_]];                                         \
        }                                                                \
    } while (0)

    // One consumer step using ECUR; issues next step's e-reads into ENXT
    // (independent ds_reads, issued after the w-reads so the compiler's
    // partial lgkm wait covers only w). Static array names -- no runtime idx.
#define STEP_PP(ECUR, ENXT, KB, J, JMAX, KK) do {                        \
        float4 wa_ = *(const float4*)&wlds[fbase];                       \
        float4 wb_ = *(const float4*)&wlds[fbase + 4];                   \
        float4 wc_ = *(const float4*)&wlds[fbase + 8];                   \
        float4 wd_ = *(const float4*)&wlds[fbase + 12];                  \
        if ((J) + 1 < (JMAX)) {                                          \
            const float* ebn_ = &ebuf[KB][(J) + 1][0];                   \
            _Pragma("unroll")                                            \
            for (int i = 0; i < 16; ++i)                                 \
                ENXT[i] = ebn_[((fbase + i) << 5) | t];                  \
        }                                                                \
        float s0_ = fmaf(ECUR[3], wa_.w, fmaf(ECUR[2], wa_.z,            \
                    fmaf(ECUR[1], wa_.y, ECUR[0] * wa_.x)));             \
        float s1_ = fmaf(ECUR[7], wb_.w, fmaf(ECUR[6], wb_.z,            \
                    fmaf(ECUR[5], wb_.y, ECUR[4] * wb_.x)));             \
        float s2_ = fmaf(ECUR[11], wc_.w, fmaf(ECUR[10], wc_.z,          \
                    fmaf(ECUR[9], wc_.y, ECUR[8] * wc_.x)));             \
        float s3_ = fmaf(ECUR[15], wd_.w, fmaf(ECUR[14], wd_.z,          \
                    fmaf(ECUR[13], wd_.y, ECUR[12] * wd_.x)));           \
        float s_ = (s0_ + s1_) + (s2_ + s3_);                            \
        s_ += __shfl_xor(s_, 32);                                        \
        wcur = s_;                                                       \
        if (lane < 32) wlds[lane] = s_;                                  \
        tg += gside[KB][J];                                              \
        const int sidx_ = 1 + (KK) * NW + (J);                           \
        if ((sidx_ & 3) == 0) RENORM;                                    \
    } while (0)

    // consumer phase: runtime j-loop (unroll-curse-free) + branch ping-pong
#define CONSUME(KK) do {                                                 \
        const int kb_ = (KK) & 1;                                        \
        const int jmax_ = min(NW, L - 1 - (KK) * NW);                    \
        float eA_[16], eB_[16];                                          \
        _Pragma("unroll")                                                \
        for (int i = 0; i < 16; ++i)                                     \
            eA_[i] = ebuf[kb_][0][((fbase + i) << 5) | t];               \
        for (int j = 0; j < jmax_; ++j) {                                \
            if ((j & 1) == 0) {                                          \
                STEP_PP(eA_, eB_, kb_, j, jmax_, KK);                    \
            } else {                                                     \
                STEP_PP(eB_, eA_, kb_, j, jmax_, KK);                    \
            }                                                            \
        }                                                                \
    } while (0)

    // One phase with buffer set (Q0..Q3,GQ): exp-write chunk KK, refill the
    // SAME regs with chunk KK+2 (first read 2 phases later), raw barrier,
    // wave-0 consume. No register rotation anywhere (proven R12).
#define PHASE(Q0, Q1, Q2, Q3, GQ, KK) do {                               \
        const int k_ = (KK);                                             \
        const int scur_ = 1 + k_ * NW + wv;                              \
        if (scur_ < L) {                                                 \
            float4* ebw = (float4*)&ebuf[k_ & 1][wv][0];                 \
            float4 e0, e1, e2, e3;                                       \
            E4(e0, Q0); E4(e1, Q1); E4(e2, Q2); E4(e3, Q3);              \
            ebw[lane] = e0; ebw[64 + lane] = e1;                         \
            ebw[128 + lane] = e2; ebw[192 + lane] = e3;                  \
            if (lane == 0) gside[k_ & 1][wv] = GQ;                       \
        }                                                                \
        TLOAD(Q0, Q1, Q2, Q3, GQ, scur_ + 2 * NW);                       \
        LGKM_BARRIER;                                                    \
        if (wv == 0) CONSUME(k_);                                        \
    } while (0)

    // ---- prologue prefetch: chunk 0 -> A, chunk 1 -> B ----
    float4 a0, a1, a2, a3, b0, b1, b2, b3;
    float ga = 0.0f, gb = 0.0f;
    TLOAD(a0, a1, a2, a3, ga, 1 + wv);
    TLOAD(b0, b1, b2, b3, gb, 1 + NW + wv);

    for (int k = 0; k < nch; k += 2) {
        PHASE(a0, a1, a2, a3, ga, k);
        if (k + 1 < nch)
            PHASE(b0, b1, b2, b3, gb, k + 1);
    }

    // ---- epilogue (consumer): logZ = ln(w[END_TAG]) + C2*ln2 ----
    if (wv == 0) {
        float wend = __shfl(wcur, END_TAG);
        float logZ = __logf(wend) + C2 * LN2;
        if (lane == 0)
            atomicAdd(out, (logZ - tg) * (1.0f / (float)B_));
    }
}

extern "C" void kernel_launch(void* const* d_in, const int* in_sizes, int n_in,
                              void* d_out, int out_size, void* d_ws, size_t ws_size,
                              hipStream_t stream) {
    const float* scores = (const float*)d_in[0];
    const int* targets  = (const int*)d_in[1];
    const void* mask    = d_in[2];
    const void* amask   = d_in[3];
    float* out = (float*)d_out;

    hipMemsetAsync(out, 0, sizeof(float), stream);
    crf_loss_kernel<<<dim3(A_ * B_), dim3(NW * 64), 0, stream>>>(
        scores, targets, mask, amask, out);
}

// Round 17
// 87.413 us; speedup vs baseline: 1.7176x; 1.7176x over previous
//
#include <hip/hip_runtime.h>

// CRF loss: A=8, S=200, B=64, T=32. scores (A,S,B,T,T) f32, targets (A,S,B) i32,
// mask (S,B) bool, a_mask (A,B) bool -- bool width (u8 vs i32) runtime-detected.
// Base = R12 (PASSED 80.5us): 8-wave block per chain, wave 0 producer+consumer,
// named A/B producer register sets (2-phase latency cover), raw lgkm-only
// barrier, runtime consumer j-loop, renorm at s%4==0.
// NEW (layout only): exp-tiles stored TRANSPOSED [t][f] with XOR swizzle
// f ^= (t&7)<<2 (4-float granularity). Consumer reads its 16 e-values as
// 4x ds_read_b128 (was 16x ds_read_b32 at stride 128B = heavy bank conflicts).
// Producers write 16 scalar ds_write_b32 (slack -- they wait at the barrier).
constexpr int A_ = 8, S_ = 200, B_ = 64, T_ = 32;
constexpr int START_TAG = 30, END_TAG = 31;
constexpr int NW = 8;                      // waves per block = tiles per phase
#define LOG2E 1.44269504088896340736f
#define LN2   0.69314718055994530942f

#if __has_builtin(__builtin_amdgcn_exp2f)
#define EXP2F(x) __builtin_amdgcn_exp2f(x)
#else
#define EXP2F(x) __expf((x) * LN2)
#endif

__device__ __forceinline__ int load_flag(const void* p, bool u8, int idx) {
    return u8 ? (int)((const unsigned char*)p)[idx] : ((const int*)p)[idx];
}

// LDS-writes-visible barrier WITHOUT vmcnt drain (proven R7/R12).
#define LGKM_BARRIER do {                                                \
        asm volatile("s_waitcnt lgkmcnt(0)" ::: "memory");               \
        __builtin_amdgcn_s_barrier();                                    \
        asm volatile("" ::: "memory");                                   \
    } while (0)

__global__ __launch_bounds__(NW * 64)
void crf_loss_kernel(const float* __restrict__ scores,
                     const int* __restrict__ targets,
                     const void* __restrict__ mask,
                     const void* __restrict__ amask,
                     float* __restrict__ out)
{
    const int chain = blockIdx.x;          // 0..511
    const int a = chain >> 6;
    const int b = chain & (B_ - 1);
    const int tid = threadIdx.x;
    const int wv = tid >> 6;               // wave 0..7 (wave 0 also consumes)
    const int lane = tid & 63;
    const int t = lane & 31;
    const int fbase = (lane >> 5) << 4;    // 0 or 16

    // bool width detect: mask row 0 is all-true. int view: 1 -> int32, 0x01010101 -> uint8
    const bool bool_u8 = (((const int*)mask)[0] != 1);
    if (!load_flag(amask, bool_u8, a * B_ + b)) return;   // uniform block exit

    __shared__ __align__(16) float ebuf[2][NW][T_ * T_];  // 2 x 8 x 4KB, [t][f^swz]
    __shared__ float gside[2][NW];                        // raw gold-path scores
    __shared__ int tg_lds[S_];
    __shared__ float wlds[T_];                            // w vector (wave 0 only)

    // ---- first false mask index L (prefix mask) ----
    int L = S_;
    for (int base = 0; base < S_; base += 64) {
        int i = base + lane;
        int mv = (i < S_) ? load_flag(mask, bool_u8, i * B_ + b) : 1;
        unsigned long long bal = __ballot(mv == 0);
        if (bal != 0ull && L == S_) L = base + (int)__builtin_ctzll(bal);
    }

    for (int i = tid; i < S_; i += NW * 64)
        tg_lds[i] = targets[((size_t)a * S_ + i) * B_ + b];
    __syncthreads();                        // tg_lds ready (drain fine in prologue)

    const size_t s_stride = (size_t)B_ * T_ * T_;         // 65536 floats per step
    const float* cb = scores + ((size_t)a * S_ * B_ + b) * (T_ * T_);

    float wcur = 0.0f, C2 = 0.0f, tg = 0.0f;
    if (wv == 0) {                          // consumer init
        wcur = EXP2F(cb[START_TAG * T_ + t] * LOG2E);
        if (lane < 32) wlds[lane] = wcur;
        tg = cb[tg_lds[0]];
    }

    const int nch = (L - 1 + NW - 1) / NW;  // phases (block-uniform)

#define E4(DST, SRC) do {                                                \
        DST.x = EXP2F(SRC.x * LOG2E); DST.y = EXP2F(SRC.y * LOG2E);      \
        DST.z = EXP2F(SRC.z * LOG2E); DST.w = EXP2F(SRC.w * LOG2E);      \
    } while (0)

#define RENORM do {                                                      \
        float m_ = wcur;                                                 \
        m_ = fmaxf(m_, __shfl_xor(m_, 1));                               \
        m_ = fmaxf(m_, __shfl_xor(m_, 2));                               \
        m_ = fmaxf(m_, __shfl_xor(m_, 4));                               \
        m_ = fmaxf(m_, __shfl_xor(m_, 8));                               \
        m_ = fmaxf(m_, __shfl_xor(m_, 16));                              \
        int eb_ = (__float_as_int(m_) >> 23) & 0xff;                     \
        C2 += (float)(eb_ - 127);                                        \
        float sc2_ = __int_as_float((254 - eb_) << 23);                  \
        wcur *= sc2_;                                                    \
        if (lane < 32) wlds[lane] = wcur;                                \
    } while (0)

#define TLOAD(Q0, Q1, Q2, Q3, GR, SC) do {                               \
        const int s_ = (SC);                                             \
        if (s_ < L) {                                                    \
            const float*  p_  = cb + (size_t)s_ * s_stride;              \
            const float4* p4_ = (const float4*)p_;                       \
            Q0 = p4_[lane];       Q1 = p4_[64 + lane];                   \
            Q2 = p4_[128 + lane]; Q3 = p4_[192 + lane];                  \
            GR = p_[tg_lds[s_]];                                         \
        }                                                                \
    } while (0)

    // consumer phase: runtime j-loop (proven form); e via 4x ds_read_b128 from
    // the transposed+swizzled tile. value at [t*32 + (X^swz)] is f = X (X 4-aligned).
#define CONSUME(KK) do {                                                 \
        const int kb_ = (KK) & 1;                                        \
        const int jmax_ = min(NW, L - 1 - (KK) * NW);                    \
        const int sw_ = (t & 7) << 2;                                    \
        const int rowb_ = t << 5;                                        \
        for (int j = 0; j < jmax_; ++j) {                                \
            const int s = 1 + (KK) * NW + j;                             \
            const float* eb = &ebuf[kb_][j][0];                          \
            float4 e0_ = *(const float4*)&eb[rowb_ + ((fbase + 0) ^ sw_)];  \
            float4 e1_ = *(const float4*)&eb[rowb_ + ((fbase + 4) ^ sw_)];  \
            float4 e2_ = *(const float4*)&eb[rowb_ + ((fbase + 8) ^ sw_)];  \
            float4 e3_ = *(const float4*)&eb[rowb_ + ((fbase + 12) ^ sw_)]; \
            float4 wa_ = *(const float4*)&wlds[fbase];                   \
            float4 wb_ = *(const float4*)&wlds[fbase + 4];               \
            float4 wc_ = *(const float4*)&wlds[fbase + 8];               \
            float4 wd_ = *(const float4*)&wlds[fbase + 12];              \
            float s0_ = fmaf(e0_.w, wa_.w, fmaf(e0_.z, wa_.z,            \
                        fmaf(e0_.y, wa_.y, e0_.x * wa_.x)));             \
            float s1_ = fmaf(e1_.w, wb_.w, fmaf(e1_.z, wb_.z,            \
                        fmaf(e1_.y, wb_.y, e1_.x * wb_.x)));             \
            float s2_ = fmaf(e2_.w, wc_.w, fmaf(e2_.z, wc_.z,            \
                        fmaf(e2_.y, wc_.y, e2_.x * wc_.x)));             \
            float s3_ = fmaf(e3_.w, wd_.w, fmaf(e3_.z, wd_.z,            \
                        fmaf(e3_.y, wd_.y, e3_.x * wd_.x)));             \
            float s_ = (s0_ + s1_) + (s2_ + s3_);                        \
            s_ += __shfl_xor(s_, 32);                                    \
            wcur = s_;                                                   \
            if (lane < 32) wlds[lane] = s_;                              \
            tg += gside[kb_][j];                                         \
            if ((s & 3) == 0) RENORM;                                    \
        }                                                                \
    } while (0)

    // One phase with buffer set (Q0..Q3,GQ): exp + TRANSPOSED swizzled write of
    // chunk KK, refill the SAME regs with chunk KK+2, raw barrier, wave-0
    // consume. No register rotation anywhere (proven R12).
    // Producer element (chunk c, comp i): f = c*8 + (lane>>3), t = 4*(lane&7)+i.
#define PHASE(Q0, Q1, Q2, Q3, GQ, KK) do {                               \
        const int k_ = (KK);                                             \
        const int scur_ = 1 + k_ * NW + wv;                              \
        if (scur_ < L) {                                                 \
            float4 e0, e1, e2, e3;                                       \
            E4(e0, Q0); E4(e1, Q1); E4(e2, Q2); E4(e3, Q3);              \
            float v0_[4] = {e0.x, e0.y, e0.z, e0.w};                     \
            float v1_[4] = {e1.x, e1.y, e1.z, e1.w};                     \
            float v2_[4] = {e2.x, e2.y, e2.z, e2.w};                     \
            float v3_[4] = {e3.x, e3.y, e3.z, e3.w};                     \
            float* ebw = &ebuf[k_ & 1][wv][0];                           \
            const int f0_ = lane >> 3;                                   \
            const int tb_ = (lane & 7) << 2;                             \
            _Pragma("unroll")                                            \
            for (int i = 0; i < 4; ++i) {                                \
                const int ti_ = tb_ + i;                                 \
                const int sx_ = (ti_ & 7) << 2;                          \
                const int rb_ = ti_ << 5;                                \
                ebw[rb_ + ((f0_ +  0) ^ sx_)] = v0_[i];                  \
                ebw[rb_ + ((f0_ +  8) ^ sx_)] = v1_[i];                  \
                ebw[rb_ + ((f0_ + 16) ^ sx_)] = v2_[i];                  \
                ebw[rb_ + ((f0_ + 24) ^ sx_)] = v3_[i];                  \
            }                                                            \
            if (lane == 0) gside[k_ & 1][wv] = GQ;                       \
        }                                                                \
        TLOAD(Q0, Q1, Q2, Q3, GQ, scur_ + 2 * NW);                       \
        LGKM_BARRIER;                                                    \
        if (wv == 0) CONSUME(k_);                                        \
    } while (0)

    // ---- prologue prefetch: chunk 0 -> A, chunk 1 -> B ----
    float4 a0, a1, a2, a3, b0, b1, b2, b3;
    float ga = 0.0f, gb = 0.0f;
    TLOAD(a0, a1, a2, a3, ga, 1 + wv);
    TLOAD(b0, b1, b2, b3, gb, 1 + NW + wv);

    for (int k = 0; k < nch; k += 2) {
        PHASE(a0, a1, a2, a3, ga, k);
        if (k + 1 < nch)
            PHASE(b0, b1, b2, b3, gb, k + 1);
    }

    // ---- epilogue (consumer): logZ = ln(w[END_TAG]) + C2*ln2 ----
    if (wv == 0) {
        float wend = __shfl(wcur, END_TAG);
        float logZ = __logf(wend) + C2 * LN2;
        if (lane == 0)
            atomicAdd(out, (logZ - tg) * (1.0f / (float)B_));
    }
}

extern "C" void kernel_launch(void* const* d_in, const int* in_sizes, int n_in,
                              void* d_out, int out_size, void* d_ws, size_t ws_size,
                              hipStream_t stream) {
    const float* scores = (const float*)d_in[0];
    const int* targets  = (const int*)d_in[1];
    const void* mask    = d_in[2];
    const void* amask   = d_in[3];
    float* out = (float*)d_out;

    hipMemsetAsync(out, 0, sizeof(float), stream);
    crf_loss_kernel<<<dim3(A_ * B_), dim3(NW * 64), 0, stream>>>(
        scores, targets, mask, amask, out);
}